// Round 1
// baseline (949.919 us; speedup 1.0000x reference)
//
#include <hip/hip_runtime.h>
#include <hip/hip_bf16.h>

constexpr int TS = 2048;   // time steps / params length
constexpr int BB = 4096;   // batch rows

// ---------------------------------------------------------------------------
// Kernel 1: compute impulse response h[0..TS) and reversed params prv[],
// single workgroup (1024 threads). Chunked: bootstrap h[0..63] in wave 0
// registers, then 31 chunk phases of {history correlation, 64x64 Toeplitz
// triangular solve via h[0..63]}.
// ---------------------------------------------------------------------------
__global__ __launch_bounds__(1024) void compute_h_kernel(
    const float* __restrict__ params,
    float* __restrict__ prv_out,
    float* __restrict__ h_out) {
  __shared__ float p_s[TS];
  __shared__ float h_s[TS];
  __shared__ float hist_s[64];
  const int tid = threadIdx.x;

  for (int i = tid; i < TS; i += 1024) p_s[i] = params[i];
  __syncthreads();

  // Bootstrap h[0..63] entirely in wave-0 registers (lane l holds h_l).
  if (tid < 64) {
    const int lane = tid;
    float h = (lane == 0) ? 1.0f : 0.0f;
    for (int m = 1; m < 64; ++m) {
      float partial = (lane < m) ? h * p_s[m - 1 - lane] : 0.0f;
      #pragma unroll
      for (int off = 32; off; off >>= 1) partial += __shfl_xor(partial, off);
      if (lane == m) h = partial;
    }
    h_s[lane] = h;
  }
  __syncthreads();

  // Chunks c = 1..31: positions n0..n0+63.
  for (int c = 1; c < TS / 64; ++c) {
    const int n0 = c * 64;
    // Hist[i] = sum_{m=0}^{n0-1} h[m] * params[n0 + i - 1 - m]
    const int i = tid >> 4;    // 0..63
    const int sub = tid & 15;  // 16 threads per position
    float acc = 0.0f;
    for (int m = sub; m < n0; m += 16) acc += h_s[m] * p_s[n0 + i - 1 - m];
    #pragma unroll
    for (int off = 8; off; off >>= 1) acc += __shfl_xor(acc, off);
    if (sub == 0) hist_s[i] = acc;
    __syncthreads();
    // h[n0+i] = sum_{r<=i} h[r] * Hist[i-r]   (64x64 triangular Toeplitz solve)
    if (tid < 64) {
      float v = 0.0f;
      for (int r = 0; r <= tid; ++r) v += h_s[r] * hist_s[tid - r];
      h_s[n0 + tid] = v;
    }
    __syncthreads();
  }

  for (int i = tid; i < TS; i += 1024) {
    h_out[i] = h_s[i];
    prv_out[i] = p_s[TS - 1 - i];
  }
}

// ---------------------------------------------------------------------------
// Kernel 2/3: triangular Toeplitz multiply.
//   REV=true  (stage A): Y[b,m] = bias + sum_{k>=m} coef[k-m] * X[b,k]
//   REV=false (stage C): Y[b,m] =        sum_{k<=m} coef[m-k] * X[b,k]
// Block tile: 128 b-rows x 64 m-cols; thread tile 8b x 4m (256 threads, 16x16).
// k processed in 64-chunks; X tile staged in LDS (row stride 68, conflict-free),
// coefficient window W (<=144 floats) staged per chunk, zero-padded at edges.
// ---------------------------------------------------------------------------
template <bool REV>
__global__ __launch_bounds__(256) void toep_mul(
    const float* __restrict__ X,
    const float* __restrict__ coefbuf,
    const float* __restrict__ biasp,
    float* __restrict__ Y) {
  __shared__ __align__(16) float s_s[128][68];
  __shared__ __align__(16) float w_s[144];

  const int tid = threadIdx.x;
  const int tx = tid & 15;   // m dimension: 4 outputs per thread
  const int ty = tid >> 4;   // b dimension: 8 rows per thread (stride 16)
  const int m0 = blockIdx.x * 64;
  const int b0 = blockIdx.y * 128;

  const float binit = REV ? biasp[0] : 0.0f;
  float acc[8][4];
  #pragma unroll
  for (int i = 0; i < 8; ++i)
    #pragma unroll
    for (int j = 0; j < 4; ++j) acc[i][j] = binit;

  const int k0_begin = REV ? m0 : 0;
  const int k0_end   = REV ? TS : (m0 + 64);

  for (int k0 = k0_begin; k0 < k0_end; k0 += 64) {
    __syncthreads();  // previous iteration's LDS reads done
    // Stage X tile: rows b0..b0+127, cols k0..k0+63
    #pragma unroll
    for (int it = 0; it < 8; ++it) {
      const int r = ty + 16 * it;
      const float4 v = *(const float4*)&X[(size_t)(b0 + r) * TS + k0 + tx * 4];
      *(float4*)&s_s[r][tx * 4] = v;
    }
    // Stage coefficient window, zero-padded.
    const int o = REV ? (k0 - m0 - 63) : (m0 - k0 - 68);
    if (tid < 144) {
      const int d = o + tid;
      w_s[tid] = ((unsigned)d < (unsigned)TS) ? coefbuf[d] : 0.0f;
    }
    __syncthreads();

    #pragma unroll 4
    for (int kk = 0; kk < 64; kk += 4) {
      const int ta = REV ? (kk + 60 - 4 * tx) : (4 * tx - kk + 64);
      const float4 wa = *(const float4*)&w_s[ta];
      const float4 wb = *(const float4*)&w_s[ta + 4];
      const float w8[8] = {wa.x, wa.y, wa.z, wa.w, wb.x, wb.y, wb.z, wb.w};
      #pragma unroll
      for (int i = 0; i < 8; ++i) {
        const int r = ty + 16 * i;
        const float4 sv = *(const float4*)&s_s[r][kk];
        const float s4[4] = {sv.x, sv.y, sv.z, sv.w};
        #pragma unroll
        for (int q = 0; q < 4; ++q) {
          #pragma unroll
          for (int j = 0; j < 4; ++j) {
            // coef for (k=k0+kk+q, m=m0+4tx+j):
            //   REV: W[(kk+63-4tx-j)+q] = w8[3+q-j]
            //  !REV: W[(4tx+j-kk+68)-q] = w8[4+j-q]
            const int widx = REV ? (3 + q - j) : (4 + j - q);
            acc[i][j] += s4[q] * w8[widx];
          }
        }
      }
    }
  }

  #pragma unroll
  for (int i = 0; i < 8; ++i) {
    float4 v = {acc[i][0], acc[i][1], acc[i][2], acc[i][3]};
    *(float4*)&Y[(size_t)(b0 + ty + 16 * i) * TS + m0 + tx * 4] = v;
  }
}

// ---------------------------------------------------------------------------
extern "C" void kernel_launch(void* const* d_in, const int* in_sizes, int n_in,
                              void* d_out, int out_size, void* d_ws, size_t ws_size,
                              hipStream_t stream) {
  const float* inputs = (const float*)d_in[0];  // [BB, TS]
  const float* params = (const float*)d_in[1];  // [TS]
  const float* bias   = (const float*)d_in[2];  // [1]
  float* out = (float*)d_out;                   // [BB, TS]

  float* u   = (float*)d_ws;                    // [BB, TS] intermediate
  float* prv = u + (size_t)BB * TS;             // [TS] reversed params
  float* h   = prv + TS;                        // [TS] impulse response

  compute_h_kernel<<<1, 1024, 0, stream>>>(params, prv, h);

  dim3 grid(TS / 64, BB / 128);
  toep_mul<true><<<grid, 256, 0, stream>>>(inputs, prv, bias, u);
  toep_mul<false><<<grid, 256, 0, stream>>>(u, h, bias, out);
}

// Round 2
// 235.640 us; speedup vs baseline: 4.0312x; 4.0312x over previous
//
#include <hip/hip_runtime.h>
#include <hip/hip_bf16.h>

typedef _Float16 f16;
typedef _Float16 f16x8 __attribute__((ext_vector_type(8)));
typedef float f32x4 __attribute__((ext_vector_type(4)));

constexpr int TS = 2048;   // time steps / params length
constexpr int BB = 4096;   // batch rows

// ---------------------------------------------------------------------------
// Kernel 1: impulse response h[0..TS) + reversed params prv[] (fp32).
// Single workgroup; chunked triangular-Toeplitz bootstrap (verified round 0).
// ---------------------------------------------------------------------------
__global__ __launch_bounds__(1024) void compute_h_kernel(
    const float* __restrict__ params,
    float* __restrict__ prv_out,
    float* __restrict__ h_out) {
  __shared__ float p_s[TS];
  __shared__ float h_s[TS];
  __shared__ float hist_s[64];
  const int tid = threadIdx.x;

  for (int i = tid; i < TS; i += 1024) p_s[i] = params[i];
  __syncthreads();

  if (tid < 64) {
    const int lane = tid;
    float h = (lane == 0) ? 1.0f : 0.0f;
    for (int m = 1; m < 64; ++m) {
      float partial = (lane < m) ? h * p_s[m - 1 - lane] : 0.0f;
      #pragma unroll
      for (int off = 32; off; off >>= 1) partial += __shfl_xor(partial, off);
      if (lane == m) h = partial;
    }
    h_s[lane] = h;
  }
  __syncthreads();

  for (int c = 1; c < TS / 64; ++c) {
    const int n0 = c * 64;
    const int i = tid >> 4;
    const int sub = tid & 15;
    float acc = 0.0f;
    for (int m = sub; m < n0; m += 16) acc += h_s[m] * p_s[n0 + i - 1 - m];
    #pragma unroll
    for (int off = 8; off; off >>= 1) acc += __shfl_xor(acc, off);
    if (sub == 0) hist_s[i] = acc;
    __syncthreads();
    if (tid < 64) {
      float v = 0.0f;
      for (int r = 0; r <= tid; ++r) v += h_s[r] * hist_s[tid - r];
      h_s[n0 + tid] = v;
    }
    __syncthreads();
  }

  for (int i = tid; i < TS; i += 1024) {
    h_out[i] = h_s[i];
    prv_out[i] = p_s[TS - 1 - i];
  }
}

// ---------------------------------------------------------------------------
// Kernel 2: X fp32 -> f16 row-major (one-time streaming conversion).
// ---------------------------------------------------------------------------
__global__ __launch_bounds__(256) void convert_x(
    const float* __restrict__ X, f16* __restrict__ Xh) {
  const size_t total = (size_t)BB * TS / 8;
  for (size_t i = (size_t)blockIdx.x * 256 + threadIdx.x; i < total;
       i += (size_t)gridDim.x * 256) {
    const float4 a = ((const float4*)X)[2 * i];
    const float4 b = ((const float4*)X)[2 * i + 1];
    f16x8 v = {(f16)a.x, (f16)a.y, (f16)a.z, (f16)a.w,
               (f16)b.x, (f16)b.y, (f16)b.z, (f16)b.w};
    *(f16x8*)(Xh + i * 8) = v;
  }
}

// ---------------------------------------------------------------------------
// Kernel 3: build the 64 distinct 64x64 f16 W tiles, PRE-SWIZZLED in global
// (byte ^= (n&7)<<4 within each 128B row) so a linear global_load_lds copy
// reproduces the swizzled LDS image.
//  blocks 0..31:  stage A (coef=prv):  W[k][n] = prv[d*64 + k - n]
//  blocks 32..63: stage C (coef=h):    W[k][n] = h  [d*64 + n - k]
// (out-of-range -> 0 handles the triangular mask)
// ---------------------------------------------------------------------------
__global__ __launch_bounds__(256) void build_wtiles(
    const float* __restrict__ prv, const float* __restrict__ h,
    char* __restrict__ Wg) {
  const int s = blockIdx.x >> 5;
  const int dlt = blockIdx.x & 31;
  const float* coef = s ? h : prv;
  const int tid = threadIdx.x;
  const int n = tid >> 2;
  const int kq = tid & 3;
  char* tile = Wg + (size_t)blockIdx.x * 8192;
  #pragma unroll
  for (int part = 0; part < 2; ++part) {
    const int k8 = kq * 16 + part * 8;
    f16x8 v;
    #pragma unroll
    for (int i = 0; i < 8; ++i) {
      const int k = k8 + i;
      const int d = s ? (dlt * 64 + n - k) : (dlt * 64 + k - n);
      v[i] = ((unsigned)d < (unsigned)TS) ? (f16)coef[d] : (f16)0.0f;
    }
    const int off = n * 128 + ((2 * k8) ^ ((n & 7) << 4));
    *(f16x8*)(tile + off) = v;
  }
}

// ---------------------------------------------------------------------------
// Kernel 4/5: MFMA triangular-Toeplitz GEMM.
//   REV=true  (stage A): u[b,m] = bias + sum_{k>=m} prv[k-m] * x[b,k] -> f16
//   REV=false (stage C): y[b,m] =        sum_{k<=m} h[m-k]  * u[b,k] -> f32
// Block: 128 rows x 64 cols, 4 waves (2x2), wave tile 64x32. BK=64.
// Column pairing (px, 31-px): every block does exactly 33 chunks (no tail
// imbalance). Staging via global_load_lds w=16 with pre-swizzled sources.
// ---------------------------------------------------------------------------
template <bool REV>
__global__ __launch_bounds__(256, 2) void toep_mfma(
    const f16* __restrict__ Xg,    // [BB][TS] f16 input (X or u)
    const char* __restrict__ Wg,   // this stage's 32 pre-swizzled tiles
    const float* __restrict__ biasp,
    void* __restrict__ Yg) {       // REV: f16 u ; !REV: float out
  __shared__ __align__(16) char Xs[16384];  // [128 rows][128 B] swizzled
  __shared__ __align__(16) char Ws[8192];   // [64 rows][128 B] swizzled

  const int tid = threadIdx.x;
  const int lane = tid & 63;
  const int wid = tid >> 6;
  const int wrow = (wid >> 1) * 64;
  const int wcol = (wid & 1) * 32;
  const int b0 = blockIdx.y * 128;
  const int px = blockIdx.x;

  const float binit = REV ? biasp[0] : 0.0f;

  for (int phase = 0; phase < 2; ++phase) {
    const int mblk = phase ? (31 - px) : px;
    const int m0 = mblk * 64;
    const int k0b = REV ? m0 : 0;
    const int k0e = REV ? TS : (m0 + 64);

    f32x4 acc[4][2];
    #pragma unroll
    for (int i = 0; i < 4; ++i)
      #pragma unroll
      for (int j = 0; j < 2; ++j) acc[i][j] = {binit, binit, binit, binit};

    for (int k0 = k0b; k0 < k0e; k0 += 64) {
      __syncthreads();  // all waves done reading LDS from previous chunk
      // ---- stage X tile: 16 x 1KB, 4 per wave, inverse-swizzled source ----
      #pragma unroll
      for (int t2 = 0; t2 < 4; ++t2) {
        const int t = wid * 4 + t2;
        const int row = t * 8 + (lane >> 3);
        const char* src = (const char*)Xg + ((size_t)(b0 + row) * TS + k0) * 2
                          + (((lane & 7) * 16) ^ ((row & 7) << 4));
        __builtin_amdgcn_global_load_lds(
            (const __attribute__((address_space(1))) unsigned int*)src,
            (__attribute__((address_space(3))) unsigned int*)(Xs + t * 1024),
            16, 0, 0);
      }
      // ---- stage W tile: 8 x 1KB, 2 per wave (already swizzled) ----
      const int dlt = (REV ? (k0 - m0) : (m0 - k0)) >> 6;
      const char* wsrc = Wg + (size_t)dlt * 8192;
      #pragma unroll
      for (int p = 0; p < 2; ++p) {
        const int t = wid * 2 + p;
        __builtin_amdgcn_global_load_lds(
            (const __attribute__((address_space(1))) unsigned int*)(wsrc + t * 1024 + lane * 16),
            (__attribute__((address_space(3))) unsigned int*)(Ws + t * 1024),
            16, 0, 0);
      }
      __syncthreads();  // compiler drains vmcnt before s_barrier

      // ---- compute: 2 K-slices of 32, 8 MFMA each ----
      #pragma unroll
      for (int ks = 0; ks < 2; ++ks) {
        const int colb = ks * 64 + ((lane >> 4) * 16);
        f16x8 af[4], bf[2];
        #pragma unroll
        for (int i = 0; i < 4; ++i) {
          const int row = wrow + i * 16 + (lane & 15);
          af[i] = *(const f16x8*)(Xs + row * 128 + (colb ^ ((row & 7) << 4)));
        }
        #pragma unroll
        for (int j = 0; j < 2; ++j) {
          const int n = wcol + j * 16 + (lane & 15);
          bf[j] = *(const f16x8*)(Ws + n * 128 + (colb ^ ((n & 7) << 4)));
        }
        #pragma unroll
        for (int i = 0; i < 4; ++i)
          #pragma unroll
          for (int j = 0; j < 2; ++j)
            acc[i][j] = __builtin_amdgcn_mfma_f32_16x16x32_f16(
                af[i], bf[j], acc[i][j], 0, 0, 0);
      }
    }

    // ---- epilogue: C/D layout col=lane&15, row=(lane>>4)*4+r ----
    #pragma unroll
    for (int i = 0; i < 4; ++i) {
      #pragma unroll
      for (int j = 0; j < 2; ++j) {
        #pragma unroll
        for (int r = 0; r < 4; ++r) {
          const int row = b0 + wrow + i * 16 + (lane >> 4) * 4 + r;
          const int col = m0 + wcol + j * 16 + (lane & 15);
          if (REV)
            ((f16*)Yg)[(size_t)row * TS + col] = (f16)acc[i][j][r];
          else
            ((float*)Yg)[(size_t)row * TS + col] = acc[i][j][r];
        }
      }
    }
  }
}

// ---------------------------------------------------------------------------
extern "C" void kernel_launch(void* const* d_in, const int* in_sizes, int n_in,
                              void* d_out, int out_size, void* d_ws, size_t ws_size,
                              hipStream_t stream) {
  const float* inputs = (const float*)d_in[0];  // [BB, TS] fp32
  const float* params = (const float*)d_in[1];  // [TS]
  const float* bias   = (const float*)d_in[2];  // [1]
  float* out = (float*)d_out;                   // [BB, TS] fp32

  char* ws = (char*)d_ws;
  f16*   Xh  = (f16*)ws;                                  // 16 MB
  f16*   u   = (f16*)(ws + (size_t)BB * TS * 2);          // 16 MB
  float* prv = (float*)(ws + (size_t)BB * TS * 4);        // 8 KB
  float* h   = prv + TS;                                  // 8 KB
  char*  Wg  = (char*)(h + TS);                           // 64 x 8 KB

  convert_x<<<2048, 256, 0, stream>>>(inputs, Xh);
  compute_h_kernel<<<1, 1024, 0, stream>>>(params, prv, h);
  build_wtiles<<<64, 256, 0, stream>>>(prv, h, Wg);

  dim3 grid(16, 32);
  toep_mfma<true><<<grid, 256, 0, stream>>>(Xh, Wg, bias, (void*)u);
  toep_mfma<false><<<grid, 256, 0, stream>>>(u, Wg + 32 * 8192, bias, (void*)out);
}

// Round 3
// 145.384 us; speedup vs baseline: 6.5339x; 1.6208x over previous
//
#include <hip/hip_runtime.h>
#include <hip/hip_bf16.h>

typedef _Float16 f16;
typedef _Float16 f16x8 __attribute__((ext_vector_type(8)));
typedef float f32x4 __attribute__((ext_vector_type(4)));

constexpr int TS = 2048;   // time steps / params length
constexpr int BB = 4096;   // batch rows

// Shared-memory union: toep path (24 KB) / h-block path (~20 KB)
union SharedU {
  struct { char Xs[16384]; char Ws[8192]; } t;
  struct {
    float rp1[2048];      // rp1[y] = p[2046-y] (y<=2046), rp1[2047]=0
    float h[2048];        // impulse response (grows chunk by chunk)
    float rhb[4][128];    // rhb[sh][y] = (y+sh<=63) ? h[63-y-sh] : 0
    float hist[64];
    float histp[4][64];   // per-wave partial hist
  } hb;
};

// ---------------------------------------------------------------------------
// toep body: triangular Toeplitz x dense GEMM via mfma_f32_16x16x32_f16.
//   REV=true  (stage A): u[b,m] = bias + sum_{k>=m} prv[k-m] * x[b,k] -> f16
//   REV=false (stage C): y[b,m] =        sum_{k<=m} h[m-k]  * u[b,k] -> f32
// Block: 128 rows x 64 cols, 4 waves (2x2), BK=64, column pairing (px,31-px).
// w in [0,512): px = w&15, by = w>>4 (caller applies XCD swizzle).
// ---------------------------------------------------------------------------
template <bool REV>
__device__ void toep_body(SharedU& lds, int w, const f16* __restrict__ Xg,
                          const char* __restrict__ Wg,
                          const float* __restrict__ biasp, void* __restrict__ Yg) {
  char* Xs = lds.t.Xs;
  char* Ws = lds.t.Ws;
  const int tid = threadIdx.x;
  const int lane = tid & 63;
  const int wid = tid >> 6;
  const int wrow = (wid >> 1) * 64;
  const int wcol = (wid & 1) * 32;
  const int px = w & 15;
  const int b0 = (w >> 4) * 128;

  float binit = 0.0f;
  if (REV) binit = biasp[0];

  for (int phase = 0; phase < 2; ++phase) {
    const int mblk = phase ? (31 - px) : px;
    const int m0 = mblk * 64;
    const int k0b = REV ? m0 : 0;
    const int k0e = REV ? TS : (m0 + 64);

    f32x4 acc[4][2];
    #pragma unroll
    for (int i = 0; i < 4; ++i)
      #pragma unroll
      for (int j = 0; j < 2; ++j) acc[i][j] = {binit, binit, binit, binit};

    for (int k0 = k0b; k0 < k0e; k0 += 64) {
      __syncthreads();
      // stage X tile: 16 x 1KB, inverse-swizzled per-lane global source
      #pragma unroll
      for (int t2 = 0; t2 < 4; ++t2) {
        const int t = wid * 4 + t2;
        const int row = t * 8 + (lane >> 3);
        const char* src = (const char*)Xg + ((size_t)(b0 + row) * TS + k0) * 2
                          + (((lane & 7) * 16) ^ ((row & 7) << 4));
        __builtin_amdgcn_global_load_lds(
            (const __attribute__((address_space(1))) unsigned int*)src,
            (__attribute__((address_space(3))) unsigned int*)(Xs + t * 1024),
            16, 0, 0);
      }
      // stage W tile (pre-swizzled in global): 8 x 1KB
      const int dlt = (REV ? (k0 - m0) : (m0 - k0)) >> 6;
      const char* wsrc = Wg + (size_t)dlt * 8192;
      #pragma unroll
      for (int p = 0; p < 2; ++p) {
        const int t = wid * 2 + p;
        __builtin_amdgcn_global_load_lds(
            (const __attribute__((address_space(1))) unsigned int*)(wsrc + t * 1024 + lane * 16),
            (__attribute__((address_space(3))) unsigned int*)(Ws + t * 1024),
            16, 0, 0);
      }
      __syncthreads();

      #pragma unroll
      for (int ks = 0; ks < 2; ++ks) {
        const int colb = ks * 64 + ((lane >> 4) * 16);
        f16x8 af[4], bf[2];
        #pragma unroll
        for (int i = 0; i < 4; ++i) {
          const int row = wrow + i * 16 + (lane & 15);
          af[i] = *(const f16x8*)(Xs + row * 128 + (colb ^ ((row & 7) << 4)));
        }
        #pragma unroll
        for (int j = 0; j < 2; ++j) {
          const int n = wcol + j * 16 + (lane & 15);
          bf[j] = *(const f16x8*)(Ws + n * 128 + (colb ^ ((n & 7) << 4)));
        }
        #pragma unroll
        for (int i = 0; i < 4; ++i)
          #pragma unroll
          for (int j = 0; j < 2; ++j)
            acc[i][j] = __builtin_amdgcn_mfma_f32_16x16x32_f16(
                af[i], bf[j], acc[i][j], 0, 0, 0);
      }
    }

    // epilogue: C/D layout col=lane&15, row=(lane>>4)*4+r
    #pragma unroll
    for (int i = 0; i < 4; ++i) {
      #pragma unroll
      for (int j = 0; j < 2; ++j) {
        #pragma unroll
        for (int r = 0; r < 4; ++r) {
          const int row = b0 + wrow + i * 16 + (lane >> 4) * 4 + r;
          const int col = m0 + wcol + j * 16 + (lane & 15);
          if (REV)
            ((f16*)Yg)[(size_t)row * TS + col] = (f16)acc[i][j][r];
          else
            ((float*)Yg)[(size_t)row * TS + col] = acc[i][j][r];
        }
      }
    }
  }
}

// ---------------------------------------------------------------------------
// h-block: computes impulse response h in one block (256 thr) with b128-tiled
// LDS access, then writes the 32 stage-C W tiles (pre-swizzled f16) to global.
// hist[i] = sum_{m<n0} h[m] * p[n0-1+i-m];  h[n0+i] = sum_{r<=i} h[r] hist[i-r]
// ---------------------------------------------------------------------------
__device__ void h_block_body(SharedU& lds, const float* __restrict__ params,
                             char* __restrict__ WgC) {
  float* rp1 = lds.hb.rp1;
  float* h_s = lds.hb.h;
  float (*rhb)[128] = lds.hb.rhb;
  float* hist_s = lds.hb.hist;
  float (*histp)[64] = lds.hb.histp;

  const int tid = threadIdx.x;
  const int lane = tid & 63;
  const int wave = tid >> 6;

  for (int y = tid; y < 2048; y += 256)
    rp1[y] = (y <= 2046) ? params[2046 - y] : 0.0f;
  __syncthreads();

  // bootstrap h[0..63] in wave 0 (p[m-1-lane] = rp1[2047-m+lane])
  if (wave == 0) {
    float hv = (lane == 0) ? 1.0f : 0.0f;
    for (int m = 1; m < 64; ++m) {
      float partial = (lane < m) ? hv * rp1[2047 - m + lane] : 0.0f;
      #pragma unroll
      for (int off = 32; off; off >>= 1) partial += __shfl_xor(partial, off);
      if (lane == m) hv = partial;
    }
    h_s[lane] = hv;
  }
  __syncthreads();

  // reversed-padded head table for the triangular solve
  for (int idx = tid; idx < 4 * 128; idx += 256) {
    const int sh = idx >> 7, y = idx & 127;
    rhb[sh][y] = (y + sh <= 63) ? h_s[63 - y - sh] : 0.0f;
  }
  __syncthreads();

  const int i0 = 8 * (tid & 7);   // 8 output positions per thread
  const int g = tid >> 3;         // 32 m-quad groups

  for (int c = 1; c < 32; ++c) {
    const int n0 = 64 * c;
    float acc[8];
    #pragma unroll
    for (int j = 0; j < 8; ++j) acc[j] = 0.0f;

    for (int mq = g; mq < 16 * c; mq += 32) {
      const int m = 4 * mq;
      const float4 h4 = *(const float4*)&h_s[m];
      const int y0 = 2040 - n0 + m - i0;
      const float4 wa = *(const float4*)&rp1[y0];
      const float4 wb = *(const float4*)&rp1[y0 + 4];
      const float4 wc = *(const float4*)&rp1[y0 + 8];
      const float w[12] = {wa.x, wa.y, wa.z, wa.w, wb.x, wb.y, wb.z, wb.w,
                           wc.x, wc.y, wc.z, wc.w};
      const float hh[4] = {h4.x, h4.y, h4.z, h4.w};
      // acc[j] += h[m+d] * p[n0-1+i0+j-m-d] = hh[d] * w[7+d-j]
      #pragma unroll
      for (int j = 0; j < 8; ++j)
        #pragma unroll
        for (int d = 0; d < 4; ++d)
          acc[j] += hh[d] * w[7 + d - j];
    }
    // reduce over the wave's 8 g-groups (lane bits 3..5)
    #pragma unroll
    for (int off = 8; off <= 32; off <<= 1)
      #pragma unroll
      for (int j = 0; j < 8; ++j) acc[j] += __shfl_xor(acc[j], off);
    if (lane < 8) {
      float4 lo = {acc[0], acc[1], acc[2], acc[3]};
      float4 hi = {acc[4], acc[5], acc[6], acc[7]};
      *(float4*)&histp[wave][lane * 8] = lo;
      *(float4*)&histp[wave][lane * 8 + 4] = hi;
    }
    __syncthreads();

    if (wave == 0) {
      const int i = lane;
      hist_s[i] = histp[0][i] + histp[1][i] + histp[2][i] + histp[3][i];
      float a2 = 0.0f;
      const int sh = (63 - i) & 3;
      const int yb = 63 - i - sh;
      #pragma unroll 4
      for (int t = 0; t < 16; ++t) {
        const float4 q4 = *(const float4*)&hist_s[4 * t];
        const float4 w4 = *(const float4*)&rhb[sh][yb + 4 * t];
        a2 += q4.x * w4.x + q4.y * w4.y + q4.z * w4.z + q4.w * w4.w;
      }
      h_s[n0 + i] = a2;
    }
    __syncthreads();
  }

  // write stage-C W tiles: W[k][n] = h[dlt*64 + n - k], pre-swizzled
  const int n = tid >> 2, kq = tid & 3;
  for (int dlt = 0; dlt < 32; ++dlt) {
    char* tile = WgC + (size_t)dlt * 8192;
    #pragma unroll
    for (int part = 0; part < 2; ++part) {
      const int k8 = kq * 16 + part * 8;
      f16x8 v;
      #pragma unroll
      for (int ii = 0; ii < 8; ++ii) {
        const int k = k8 + ii;
        const int dd = dlt * 64 + n - k;
        v[ii] = ((unsigned)dd < (unsigned)TS) ? (f16)h_s[dd] : (f16)0.0f;
      }
      *(f16x8*)(tile + n * 128 + ((2 * k8) ^ ((n & 7) << 4))) = v;
    }
  }
}

// ---------------------------------------------------------------------------
// Kernel 1: convert X to f16 (blocks 0..2047) + build stage-A W tiles
// (blocks 2048..2079): W_A[k][n] = prv[dlt*64+k-n] = p[2047-(dlt*64+k-n)].
// ---------------------------------------------------------------------------
__global__ __launch_bounds__(256) void conv_prep(
    const float* __restrict__ X, f16* __restrict__ Xh,
    const float* __restrict__ params, char* __restrict__ Wg) {
  const int b = blockIdx.x;
  const int tid = threadIdx.x;
  if (b < 2048) {
    const size_t base = ((size_t)b * 256 + tid) * 16;
    const float4 a0 = *(const float4*)&X[base];
    const float4 a1 = *(const float4*)&X[base + 4];
    const float4 a2 = *(const float4*)&X[base + 8];
    const float4 a3 = *(const float4*)&X[base + 12];
    f16x8 v0 = {(f16)a0.x, (f16)a0.y, (f16)a0.z, (f16)a0.w,
                (f16)a1.x, (f16)a1.y, (f16)a1.z, (f16)a1.w};
    f16x8 v1 = {(f16)a2.x, (f16)a2.y, (f16)a2.z, (f16)a2.w,
                (f16)a3.x, (f16)a3.y, (f16)a3.z, (f16)a3.w};
    *(f16x8*)&Xh[base] = v0;
    *(f16x8*)&Xh[base + 8] = v1;
  } else {
    const int dlt = b - 2048;
    char* tile = Wg + (size_t)dlt * 8192;
    const int n = tid >> 2, kq = tid & 3;
    #pragma unroll
    for (int part = 0; part < 2; ++part) {
      const int k8 = kq * 16 + part * 8;
      f16x8 v;
      #pragma unroll
      for (int ii = 0; ii < 8; ++ii) {
        const int k = k8 + ii;
        const int dd = dlt * 64 + k - n;
        v[ii] = ((unsigned)dd < (unsigned)TS) ? (f16)params[2047 - dd] : (f16)0.0f;
      }
      *(f16x8*)(tile + n * 128 + ((2 * k8) ^ ((n & 7) << 4))) = v;
    }
  }
}

// ---------------------------------------------------------------------------
// Kernel 2: mega stage A. Block 0 = h computation + C-tile build;
// blocks 1..512 = stage-A MFMA GEMM with XCD-grouped work mapping.
// ---------------------------------------------------------------------------
__global__ __launch_bounds__(256, 2) void mega_A(
    const f16* __restrict__ Xh, char* __restrict__ Wg,
    const float* __restrict__ biasp, f16* __restrict__ u,
    const float* __restrict__ params) {
  __shared__ SharedU lds;
  const int b = blockIdx.x;
  if (b == 0) {
    h_block_body(lds, params, Wg + 32 * 8192);
    return;
  }
  // XCD swizzle over b in [1,512]: XCD x = b%8 gets w in [64x, 64x+64)
  const int x = b & 7;
  const int j = (b >> 3) - (x == 0 ? 1 : 0);
  toep_body<true>(lds, x * 64 + j, Xh, Wg, biasp, (void*)u);
}

// ---------------------------------------------------------------------------
// Kernel 3: stage C MFMA GEMM.
// ---------------------------------------------------------------------------
__global__ __launch_bounds__(256, 2) void toep_C(
    const f16* __restrict__ u, const char* __restrict__ WgC,
    float* __restrict__ out) {
  __shared__ SharedU lds;
  const int b = blockIdx.x;
  const int x = b & 7;
  const int j = b >> 3;
  toep_body<false>(lds, x * 64 + j, u, WgC, nullptr, (void*)out);
}

// ---------------------------------------------------------------------------
extern "C" void kernel_launch(void* const* d_in, const int* in_sizes, int n_in,
                              void* d_out, int out_size, void* d_ws, size_t ws_size,
                              hipStream_t stream) {
  const float* inputs = (const float*)d_in[0];  // [BB, TS] fp32
  const float* params = (const float*)d_in[1];  // [TS]
  const float* bias   = (const float*)d_in[2];  // [1]
  float* out = (float*)d_out;                   // [BB, TS] fp32

  char* ws = (char*)d_ws;
  f16*  Xh = (f16*)ws;                             // 16 MB
  f16*  u  = (f16*)(ws + (size_t)BB * TS * 2);     // 16 MB
  char* Wg = ws + (size_t)BB * TS * 4;             // 64 x 8 KB (A: 0..31, C: 32..63)

  conv_prep<<<2080, 256, 0, stream>>>(inputs, Xh, params, Wg);
  mega_A<<<513, 256, 0, stream>>>(Xh, Wg, bias, u, params);
  toep_C<<<512, 256, 0, stream>>>(u, Wg + 32 * 8192, out);
}

// Round 4
// 113.350 us; speedup vs baseline: 8.3804x; 1.2826x over previous
//
#include <hip/hip_runtime.h>
#include <hip/hip_bf16.h>

typedef _Float16 f16;
typedef _Float16 f16x8 __attribute__((ext_vector_type(8)));
typedef float f32x4 __attribute__((ext_vector_type(4)));

constexpr int TS = 2048;   // time steps / params length
constexpr int BB = 4096;   // batch rows

// chunk-index XOR swizzle: spreads stride-32-float window reads across bank
// groups (16-way conflict -> conflict-free). Bijective on any 64-chunk line.
__device__ __forceinline__ int swz4(int c) { return c ^ ((c >> 3) & 7); }

struct ToepShared { char Xs[16384]; char Ws[8192]; };

// ---------------------------------------------------------------------------
// toep body: triangular Toeplitz x dense GEMM via mfma_f32_16x16x32_f16.
//   REV=true  (stage A): u[b,m] = bias + sum_{k>=m} prv[k-m] * x[b,k] -> f16
//   REV=false (stage C): y[b,m] =        sum_{k<=m} h[m-k]  * u[b,k] -> f32
// Block: 128 rows x 64 cols, 4 waves (2x2), BK=64, column pairing (px,31-px).
// ---------------------------------------------------------------------------
template <bool REV>
__device__ void toep_body(ToepShared& lds, int w, const f16* __restrict__ Xg,
                          const char* __restrict__ Wg,
                          const float* __restrict__ biasp, void* __restrict__ Yg) {
  char* Xs = lds.Xs;
  char* Ws = lds.Ws;
  const int tid = threadIdx.x;
  const int lane = tid & 63;
  const int wid = tid >> 6;
  const int wrow = (wid >> 1) * 64;
  const int wcol = (wid & 1) * 32;
  const int px = w & 15;
  const int b0 = (w >> 4) * 128;

  float binit = 0.0f;
  if (REV) binit = biasp[0];

  for (int phase = 0; phase < 2; ++phase) {
    const int mblk = phase ? (31 - px) : px;
    const int m0 = mblk * 64;
    const int k0b = REV ? m0 : 0;
    const int k0e = REV ? TS : (m0 + 64);

    f32x4 acc[4][2];
    #pragma unroll
    for (int i = 0; i < 4; ++i)
      #pragma unroll
      for (int j = 0; j < 2; ++j) acc[i][j] = {binit, binit, binit, binit};

    for (int k0 = k0b; k0 < k0e; k0 += 64) {
      __syncthreads();
      // stage X tile: 16 x 1KB, inverse-swizzled per-lane global source
      #pragma unroll
      for (int t2 = 0; t2 < 4; ++t2) {
        const int t = wid * 4 + t2;
        const int row = t * 8 + (lane >> 3);
        const char* src = (const char*)Xg + ((size_t)(b0 + row) * TS + k0) * 2
                          + (((lane & 7) * 16) ^ ((row & 7) << 4));
        __builtin_amdgcn_global_load_lds(
            (const __attribute__((address_space(1))) unsigned int*)src,
            (__attribute__((address_space(3))) unsigned int*)(Xs + t * 1024),
            16, 0, 0);
      }
      // stage W tile (pre-swizzled in global): 8 x 1KB
      const int dlt = (REV ? (k0 - m0) : (m0 - k0)) >> 6;
      const char* wsrc = Wg + (size_t)dlt * 8192;
      #pragma unroll
      for (int p = 0; p < 2; ++p) {
        const int t = wid * 2 + p;
        __builtin_amdgcn_global_load_lds(
            (const __attribute__((address_space(1))) unsigned int*)(wsrc + t * 1024 + lane * 16),
            (__attribute__((address_space(3))) unsigned int*)(Ws + t * 1024),
            16, 0, 0);
      }
      __syncthreads();

      #pragma unroll
      for (int ks = 0; ks < 2; ++ks) {
        const int colb = ks * 64 + ((lane >> 4) * 16);
        f16x8 af[4], bf[2];
        #pragma unroll
        for (int i = 0; i < 4; ++i) {
          const int row = wrow + i * 16 + (lane & 15);
          af[i] = *(const f16x8*)(Xs + row * 128 + (colb ^ ((row & 7) << 4)));
        }
        #pragma unroll
        for (int j = 0; j < 2; ++j) {
          const int n = wcol + j * 16 + (lane & 15);
          bf[j] = *(const f16x8*)(Ws + n * 128 + (colb ^ ((n & 7) << 4)));
        }
        #pragma unroll
        for (int i = 0; i < 4; ++i)
          #pragma unroll
          for (int j = 0; j < 2; ++j)
            acc[i][j] = __builtin_amdgcn_mfma_f32_16x16x32_f16(
                af[i], bf[j], acc[i][j], 0, 0, 0);
      }
    }

    // epilogue: C/D layout col=lane&15, row=(lane>>4)*4+r
    #pragma unroll
    for (int i = 0; i < 4; ++i) {
      #pragma unroll
      for (int j = 0; j < 2; ++j) {
        #pragma unroll
        for (int r = 0; r < 4; ++r) {
          const int row = b0 + wrow + i * 16 + (lane >> 4) * 4 + r;
          const int col = m0 + wcol + j * 16 + (lane & 15);
          if (REV)
            ((f16*)Yg)[(size_t)row * TS + col] = (f16)acc[i][j][r];
          else
            ((float*)Yg)[(size_t)row * TS + col] = acc[i][j][r];
        }
      }
    }
  }
}

// ---------------------------------------------------------------------------
// Kernel 1 (prep): blocks 0..511 convert X fp32->f16; block 512 builds the 32
// stage-A W tiles; block 513 computes h by 6 doubling phases (1024 threads,
// 16x16 register tiles, swizzled window buffers) and writes stage-C W tiles.
//   doubling n -> 2n:  hist[i] = sum_{m<n} h[m] p[n-1+i-m]      (i in [0,n))
//                      h[n+i]  = sum_{r<=i} h[r] hist[i-r]
// ---------------------------------------------------------------------------
__global__ __launch_bounds__(1024) void prep_kernel(
    const float* __restrict__ X, f16* __restrict__ Xh,
    const float* __restrict__ params, char* __restrict__ Wg) {
  const int b = blockIdx.x;
  const int tid = threadIdx.x;

  if (b < 512) {  // ---- X conversion ----
    const size_t base = ((size_t)b * 1024 + tid) * 16;
    const float4 a0 = *(const float4*)&X[base];
    const float4 a1 = *(const float4*)&X[base + 4];
    const float4 a2 = *(const float4*)&X[base + 8];
    const float4 a3 = *(const float4*)&X[base + 12];
    f16x8 v0 = {(f16)a0.x, (f16)a0.y, (f16)a0.z, (f16)a0.w,
                (f16)a1.x, (f16)a1.y, (f16)a1.z, (f16)a1.w};
    f16x8 v1 = {(f16)a2.x, (f16)a2.y, (f16)a2.z, (f16)a2.w,
                (f16)a3.x, (f16)a3.y, (f16)a3.z, (f16)a3.w};
    *(f16x8*)&Xh[base] = v0;
    *(f16x8*)&Xh[base + 8] = v1;
    return;
  }

  if (b == 512) {  // ---- stage-A W tiles: W[k][n] = p[2047-(dlt*64+k-n)] ----
    const int s2 = tid & 255;
    const int n = s2 >> 2, kq = s2 & 3;
    for (int dlt = tid >> 8; dlt < 32; dlt += 4) {
      char* tile = Wg + (size_t)dlt * 8192;
      #pragma unroll
      for (int part = 0; part < 2; ++part) {
        const int k8 = kq * 16 + part * 8;
        f16x8 v;
        #pragma unroll
        for (int ii = 0; ii < 8; ++ii) {
          const int k = k8 + ii;
          const int dd = dlt * 64 + k - n;
          v[ii] = ((unsigned)dd < (unsigned)TS) ? (f16)params[2047 - dd] : (f16)0.0f;
        }
        *(f16x8*)(tile + n * 128 + ((2 * k8) ^ ((n & 7) << 4))) = v;
      }
    }
    return;
  }

  // ---- b == 513: h computation ----
  __shared__ __align__(16) float rp1[2048];   // swizzled: rp1[y] = p[2046-y]
  __shared__ __align__(16) float h_s[2048];   // linear
  __shared__ __align__(16) float hist[1024];  // linear
  __shared__ __align__(16) float hb[2052];    // swizzled padded hist window

  const int lane = tid & 63;
  const int wave = tid >> 6;

  if (tid < 512) {  // init rp1, chunk per thread
    const int y = tid * 4;
    f32x4 v;
    v[0] = params[2046 - y];
    v[1] = params[2045 - y];
    v[2] = params[2044 - y];
    v[3] = (y + 3 < 2047) ? params[2043 - y] : 0.0f;
    *(f32x4*)&rp1[swz4(tid) * 4] = v;
  }
  __syncthreads();

  // bootstrap h[0..31] in wave 0: h[m] = sum_{l<m} h[l] p[m-1-l]
  if (wave == 0) {
    float hv = (lane == 0) ? 1.0f : 0.0f;
    for (int m = 1; m < 32; ++m) {
      float partial = 0.0f;
      if (lane < m) {
        const int yi = 2047 - m + lane;  // p[m-1-lane]
        partial = hv * rp1[swz4(yi >> 2) * 4 + (yi & 3)];
      }
      #pragma unroll
      for (int off = 32; off; off >>= 1) partial += __shfl_xor(partial, off);
      if (lane == m) hv = partial;
    }
    if (lane < 32) h_s[lane] = hv;
  }
  __syncthreads();

  const int sub = tid & 7;
  const int gi = tid >> 3;

  for (int n = 32; n < 2048; n <<= 1) {
    const int ng16 = n >> 4;
    const int T = (n >= 128) ? (n >> 7) : 1;

    // ---------- phase H: hist ----------
    if (gi < ng16) {
      float acc[16];
      #pragma unroll
      for (int j = 0; j < 16; ++j) acc[j] = 0.0f;
      const int ybase = (2047 - n) - gi * 16 - 15;
      for (int t = 0; t < T; ++t) {
        const int m16 = (sub + 8 * t) * 16;
        if (m16 < n) {
          const int c0 = (ybase + m16) >> 2;
          f32x4 wv[8];
          #pragma unroll
          for (int q = 0; q < 8; ++q) wv[q] = *(const f32x4*)&rp1[swz4(c0 + q) * 4];
          f32x4 hv4[4];
          #pragma unroll
          for (int q = 0; q < 4; ++q) hv4[q] = *(const f32x4*)&h_s[m16 + 4 * q];
          #pragma unroll
          for (int d = 0; d < 16; ++d) {
            const float hd = hv4[d >> 2][d & 3];
            #pragma unroll
            for (int j = 0; j < 16; ++j) {
              const int k = d - j + 15;  // w[k] = rp1[ybase+m16+k] = p[n-1+i-m]
              acc[j] += hd * wv[k >> 2][k & 3];
            }
          }
        }
      }
      #pragma unroll
      for (int j = 0; j < 16; ++j) {
        acc[j] += __shfl_xor(acc[j], 1);
        acc[j] += __shfl_xor(acc[j], 2);
        acc[j] += __shfl_xor(acc[j], 4);
      }
      if (sub == 0) {
        #pragma unroll
        for (int q = 0; q < 4; ++q) {
          f32x4 v = {acc[4 * q], acc[4 * q + 1], acc[4 * q + 2], acc[4 * q + 3]};
          *(f32x4*)&hist[gi * 16 + 4 * q] = v;
        }
      }
    }
    __syncthreads();

    // ---------- build padded window buffer hb[y] = hist[y-P], P = n+3 ----------
    const int P = n + 3;
    const int nchunk = (2 * n + 4) >> 2;
    for (int c = tid; c < nchunk; c += 1024) {
      f32x4 v;
      #pragma unroll
      for (int q = 0; q < 4; ++q) {
        const int idx = 4 * c + q - P;
        v[q] = ((unsigned)idx < (unsigned)n) ? hist[idx] : 0.0f;
      }
      *(f32x4*)&hb[swz4(c) * 4] = v;
    }
    __syncthreads();

    // ---------- phase S: h[n+i] = sum_{r<=i} h[r] hist[i-r] ----------
    if (gi < ng16) {
      float acc[16];
      #pragma unroll
      for (int j = 0; j < 16; ++j) acc[j] = 0.0f;
      int t_end = (gi >= sub) ? (((gi - sub) >> 3) + 1) : 0;
      if (t_end > T) t_end = T;
      const int ybase = P + gi * 16 - 15;
      for (int t = 0; t < t_end; ++t) {
        const int r16 = (sub + 8 * t) * 16;
        const int c0 = (ybase - r16) >> 2;
        f32x4 wv[8];
        #pragma unroll
        for (int q = 0; q < 8; ++q) wv[q] = *(const f32x4*)&hb[swz4(c0 + q) * 4];
        f32x4 hv4[4];
        #pragma unroll
        for (int q = 0; q < 4; ++q) hv4[q] = *(const f32x4*)&h_s[r16 + 4 * q];
        #pragma unroll
        for (int d = 0; d < 16; ++d) {
          const float hd = hv4[d >> 2][d & 3];
          #pragma unroll
          for (int j = 0; j < 16; ++j) {
            const int k = j - d + 15;  // hb[ybase-r16+k] = hist[i-r] (0 if r>i)
            acc[j] += hd * wv[k >> 2][k & 3];
          }
        }
      }
      #pragma unroll
      for (int j = 0; j < 16; ++j) {
        acc[j] += __shfl_xor(acc[j], 1);
        acc[j] += __shfl_xor(acc[j], 2);
        acc[j] += __shfl_xor(acc[j], 4);
      }
      if (sub == 0) {
        #pragma unroll
        for (int q = 0; q < 4; ++q) {
          f32x4 v = {acc[4 * q], acc[4 * q + 1], acc[4 * q + 2], acc[4 * q + 3]};
          *(f32x4*)&h_s[n + gi * 16 + 4 * q] = v;
        }
      }
    }
    __syncthreads();
  }

  // ---- stage-C W tiles: W[k][n] = h[dlt*64 + n - k], pre-swizzled ----
  {
    const int s2 = tid & 255;
    const int n2 = s2 >> 2, kq = s2 & 3;
    char* WgC = Wg + 32 * 8192;
    for (int dlt = tid >> 8; dlt < 32; dlt += 4) {
      char* tile = WgC + (size_t)dlt * 8192;
      #pragma unroll
      for (int part = 0; part < 2; ++part) {
        const int k8 = kq * 16 + part * 8;
        f16x8 v;
        #pragma unroll
        for (int ii = 0; ii < 8; ++ii) {
          const int k = k8 + ii;
          const int dd = dlt * 64 + n2 - k;
          v[ii] = ((unsigned)dd < (unsigned)TS) ? (f16)h_s[dd] : (f16)0.0f;
        }
        *(f16x8*)(tile + n2 * 128 + ((2 * k8) ^ ((n2 & 7) << 4))) = v;
      }
    }
  }
}

// ---------------------------------------------------------------------------
// Kernel 2/3: stage A / stage C MFMA GEMMs with XCD-grouped work mapping.
// ---------------------------------------------------------------------------
__global__ __launch_bounds__(256, 2) void toep_A(
    const f16* __restrict__ Xh, const char* __restrict__ Wg,
    const float* __restrict__ biasp, f16* __restrict__ u) {
  __shared__ ToepShared lds;
  const int b = blockIdx.x;
  toep_body<true>(lds, (b & 7) * 64 + (b >> 3), Xh, Wg, biasp, (void*)u);
}

__global__ __launch_bounds__(256, 2) void toep_C(
    const f16* __restrict__ u, const char* __restrict__ WgC,
    float* __restrict__ out) {
  __shared__ ToepShared lds;
  const int b = blockIdx.x;
  toep_body<false>(lds, (b & 7) * 64 + (b >> 3), u, WgC, nullptr, (void*)out);
}

// ---------------------------------------------------------------------------
extern "C" void kernel_launch(void* const* d_in, const int* in_sizes, int n_in,
                              void* d_out, int out_size, void* d_ws, size_t ws_size,
                              hipStream_t stream) {
  const float* inputs = (const float*)d_in[0];  // [BB, TS] fp32
  const float* params = (const float*)d_in[1];  // [TS]
  const float* bias   = (const float*)d_in[2];  // [1]
  float* out = (float*)d_out;                   // [BB, TS] fp32

  char* ws = (char*)d_ws;
  f16*  Xh = (f16*)ws;                             // 16 MB
  f16*  u  = (f16*)(ws + (size_t)BB * TS * 2);     // 16 MB
  char* Wg = ws + (size_t)BB * TS * 4;             // 64 x 8 KB (A: 0..31, C: 32..63)

  prep_kernel<<<514, 1024, 0, stream>>>(inputs, Xh, params, Wg);
  toep_A<<<512, 256, 0, stream>>>(Xh, Wg, bias, u);
  toep_C<<<512, 256, 0, stream>>>(u, Wg + 32 * 8192, out);
}